// Round 5
// baseline (126.880 us; speedup 1.0000x reference)
//
#include <hip/hip_runtime.h>
#include <stdint.h>

// ---------------------------------------------------------------------------
// AVNNType1Linear: out[b,o,0] = relu(sum_k x[b,k,0]*W[o,k] + bias[o])
//                  out[b,o,1] = (sum_k x[b,k,0] + sum_k x[b,k,1]) / (2*K)
// M=2048, N=4096, K=4096 fp32.
// r5 design: LDS-FREE MFMA GEMM. Convert kernels write bf16 operands in
// MFMA-fragment-major layout; GEMM loads fragments global->VGPR coalesced,
// register double-buffered, no barriers. (r4 hit the LDS-port BW wall.)
// Fragment layout (16B granules): [strip=row/64][ks=k/32][rfrag=(row%64)/16]
//   [lane]  where lane = (row%16) | (((k%32)/8)<<4), granule = 8 bf16.
// ---------------------------------------------------------------------------

typedef __bf16 bf16x8_t __attribute__((ext_vector_type(8)));
typedef float f32x4_t __attribute__((ext_vector_type(4)));

__device__ __forceinline__ uint32_t f32_to_bf16_rne(float f) {
    uint32_t u = __float_as_uint(f);
    return (u + 0x7fffu + ((u >> 16) & 1u)) >> 16;
}

// ---- convert kernels: fp32 -> bf16 fragment-major (+ row stats for x) ----
// STATS: src = x [rows][K][2] (ch0 packed, both channels summed)
// else : src = W [rows][K]
template <bool STATS>
__global__ __launch_bounds__(256) void convert_frag(
    const float* __restrict__ src, uint4* __restrict__ dst,
    float* __restrict__ val, int K, int spb) {
    const int t = threadIdx.x;
    const int rbase = blockIdx.x * 16;
    const int r16 = t & 15, og = t >> 4;          // og 0..15
    const int row = rbase + r16;
    const int ksn = K >> 5;
    const int strip = row >> 6, rfrag = (row >> 4) & 3;
    float s = 0.f;
    const int st0 = blockIdx.y * spb;
    for (int st = st0; st < st0 + spb; ++st) {
        const int o = og + st * 16;               // k-octet index
        const int k = o * 8;
        uint32_t pk[4];
        if (STATS) {
            const float4* p = (const float4*)(src + ((size_t)row * K + k) * 2);
#pragma unroll
            for (int i = 0; i < 4; ++i) {
                float4 v = p[i];
                s += (v.x + v.y) + (v.z + v.w);
                pk[i] = f32_to_bf16_rne(v.x) | (f32_to_bf16_rne(v.z) << 16);
            }
        } else {
            const float4* p = (const float4*)(src + (size_t)row * K + k);
#pragma unroll
            for (int i = 0; i < 2; ++i) {
                float4 v = p[i];
                pk[2 * i]     = f32_to_bf16_rne(v.x) | (f32_to_bf16_rne(v.y) << 16);
                pk[2 * i + 1] = f32_to_bf16_rne(v.z) | (f32_to_bf16_rne(v.w) << 16);
            }
        }
        const int ks = o >> 2;
        const int ln = r16 | ((o & 3) << 4);
        dst[((size_t)(strip * ksn + ks) * 4 + rfrag) * 64 + ln] =
            make_uint4(pk[0], pk[1], pk[2], pk[3]);
    }
    if (STATS) {
        s += __shfl_xor(s, 16, 64);
        s += __shfl_xor(s, 32, 64);
        __shared__ float red[4][16];
        if ((t & 48) == 0) red[t >> 6][r16] = s;
        __syncthreads();
        if (t < 16) {
            float p = red[0][t] + red[1][t] + red[2][t] + red[3][t];
            atomicAdd(&val[rbase + t], p / (float)(2 * K));
        }
    }
}

// ---- LDS-free fragment GEMM: 128x128 block, 4 waves (2m x 2n), wave 64x64 ---
__global__ __launch_bounds__(256, 2) void gemm_frag(
    const uint4* __restrict__ Af, const uint4* __restrict__ Bf,
    const float* __restrict__ bias, const float* __restrict__ val,
    float* __restrict__ out, int M, int N, int K) {
    const int tid = threadIdx.x;
    const int wv = tid >> 6;
    const int lane = tid & 63;
    const int lrow = lane & 15, lkg = lane >> 4;
    const int nbx = N >> 7, nby = M >> 7;
    const int nwg = nbx * nby;

    // XCD-aware remap: each XCD gets a contiguous wg-chunk; decompose
    // y-fastest so an XCD's blocks share a B-column panel.
    int wg = blockIdx.x;
    if ((nwg & 7) == 0) {
        const int cpx = nwg >> 3;
        wg = (wg & 7) * cpx + (wg >> 3);
    }
    const int y = wg % nby, x = wg / nby;
    const int m0 = y * 128, n0 = x * 128;
    const int wr = wv >> 1, wc = wv & 1;

    const int ksn = K >> 5;
    const bf16x8_t* awp = (const bf16x8_t*)Af +
        ((size_t)((m0 >> 6) + wr) * ksn * 4) * 64 + lane;
    const bf16x8_t* bwp = (const bf16x8_t*)Bf +
        ((size_t)((n0 >> 6) + wc) * ksn * 4) * 64 + lane;

    f32x4_t acc[4][4];
#pragma unroll
    for (int i = 0; i < 4; ++i)
#pragma unroll
        for (int j = 0; j < 4; ++j) acc[i][j] = (f32x4_t){0.f, 0.f, 0.f, 0.f};

    const int NT = K >> 6;   // K-tiles of 64 (2 ks-steps each)
    bf16x8_t A0[8], B0[8], A1[8], B1[8];

#define LOADF(Ad, Bd, tt)                                                     \
    {                                                                         \
        const bf16x8_t* ap = awp + (size_t)(tt) * 512;                        \
        const bf16x8_t* bp = bwp + (size_t)(tt) * 512;                        \
        _Pragma("unroll") for (int q = 0; q < 8; ++q) {                       \
            Ad[q] = ap[q * 64];                                               \
            Bd[q] = bp[q * 64];                                               \
        }                                                                     \
    }
#define MMF(Aa, Bb)                                                           \
    {                                                                         \
        __builtin_amdgcn_s_setprio(1);                                        \
        _Pragma("unroll") for (int s = 0; s < 2; ++s)                         \
            _Pragma("unroll") for (int m = 0; m < 4; ++m)                     \
                _Pragma("unroll") for (int n = 0; n < 4; ++n)                 \
                    acc[m][n] = __builtin_amdgcn_mfma_f32_16x16x32_bf16(      \
                        Aa[s * 4 + m], Bb[s * 4 + n], acc[m][n], 0, 0, 0);    \
        __builtin_amdgcn_s_setprio(0);                                        \
    }

    LOADF(A0, B0, 0);
    for (int t = 0; t < NT; t += 2) {
        if (t + 1 < NT) LOADF(A1, B1, t + 1);
        MMF(A0, B0);
        if (t + 2 < NT) LOADF(A0, B0, t + 2);
        if (t + 1 < NT) MMF(A1, B1);
    }
#undef LOADF
#undef MMF

    // ---------------- epilogue: bias + relu + val interleave ----------------
    const int gmb = m0 + wr * 64;
    const int gnb = n0 + wc * 64;
    float bcol[4];
#pragma unroll
    for (int n = 0; n < 4; ++n) bcol[n] = bias[gnb + n * 16 + lrow];
#pragma unroll
    for (int m = 0; m < 4; ++m) {
#pragma unroll
        for (int r = 0; r < 4; ++r) {
            const int row = gmb + m * 16 + lkg * 4 + r;
            const float vr = val[row];
            float2* orow = (float2*)(out + (size_t)row * N * 2);
#pragma unroll
            for (int n = 0; n < 4; ++n) {
                const int col = gnb + n * 16 + lrow;
                float a = fmaxf(acc[m][n][r] + bcol[n], 0.f);
                orow[col] = make_float2(a, vr);
            }
        }
    }
}

// ---- fallback kernels (small ws): r0 path, known-correct ----
__global__ __launch_bounds__(256) void convert_x_stats(
    const float4* __restrict__ x4, uint32_t* __restrict__ abf,
    float* __restrict__ val, int din) {
    const int row = blockIdx.x;
    const int t = threadIdx.x;
    const int f4pr = din >> 1;
    const float4* xr = x4 + (size_t)row * f4pr;
    float s = 0.f;
    for (int i = t; i < f4pr; i += 256) {
        float4 v = xr[i];
        s += (v.x + v.y) + (v.z + v.w);
    }
#pragma unroll
    for (int off = 32; off; off >>= 1) s += __shfl_down(s, off, 64);
    __shared__ float red[4];
    if ((t & 63) == 0) red[t >> 6] = s;
    __syncthreads();
    if (t == 0) val[row] = (red[0] + red[1] + red[2] + red[3]) / (float)(2 * din);
}

__global__ __launch_bounds__(256) void gemm_fallback(
    const float* __restrict__ xf, const float* __restrict__ Wf,
    const float* __restrict__ bias, const float* __restrict__ val,
    float* __restrict__ out, int M, int N, int K) {
    __shared__ uint16_t lA[128 * 32];
    __shared__ uint16_t lB[128 * 32];
    const int tid = threadIdx.x;
    const int wv = tid >> 6;
    const int lane = tid & 63;
    const int lrow = lane & 15;
    const int lkg = lane >> 4;
    const int m0 = blockIdx.y * 128;
    const int n0 = blockIdx.x * 128;
    const int wr = wv >> 1, wc = wv & 1;
    f32x4_t acc[4][4];
#pragma unroll
    for (int i = 0; i < 4; ++i)
#pragma unroll
        for (int j = 0; j < 4; ++j) acc[i][j] = (f32x4_t){0.f, 0.f, 0.f, 0.f};
    for (int k0 = 0; k0 < K; k0 += 32) {
        float4 va[8];
        float4 vb[4];
#pragma unroll
        for (int i = 0; i < 8; ++i) {
            const int p = i * 256 + tid;
            const int row = p >> 4, pc = p & 15;
            va[i] = *(const float4*)(xf + ((size_t)(m0 + row) * K + k0 + pc * 2) * 2);
        }
#pragma unroll
        for (int i = 0; i < 4; ++i) {
            const int q = i * 256 + tid;
            const int row = q >> 3, qc = q & 7;
            vb[i] = *(const float4*)(Wf + (size_t)(n0 + row) * K + k0 + qc * 4);
        }
        __syncthreads();
#pragma unroll
        for (int i = 0; i < 8; ++i) {
            const int p = i * 256 + tid;
            const int row = p >> 4, pc = p & 15;
            *(uint32_t*)&lA[row * 32 + pc * 2] =
                f32_to_bf16_rne(va[i].x) | (f32_to_bf16_rne(va[i].z) << 16);
        }
#pragma unroll
        for (int i = 0; i < 4; ++i) {
            const int q = i * 256 + tid;
            const int row = q >> 3, qc = q & 7;
            uint2 pk;
            pk.x = f32_to_bf16_rne(vb[i].x) | (f32_to_bf16_rne(vb[i].y) << 16);
            pk.y = f32_to_bf16_rne(vb[i].z) | (f32_to_bf16_rne(vb[i].w) << 16);
            *(uint2*)&lB[row * 32 + qc * 4] = pk;
        }
        __syncthreads();
        bf16x8_t af[4], bfr[4];
#pragma unroll
        for (int i = 0; i < 4; ++i)
            af[i] = *(const bf16x8_t*)&lA[(wr * 64 + i * 16 + lrow) * 32 + lkg * 8];
#pragma unroll
        for (int j = 0; j < 4; ++j)
            bfr[j] = *(const bf16x8_t*)&lB[(wc * 64 + j * 16 + lrow) * 32 + lkg * 8];
#pragma unroll
        for (int i = 0; i < 4; ++i)
#pragma unroll
            for (int j = 0; j < 4; ++j)
                acc[i][j] = __builtin_amdgcn_mfma_f32_16x16x32_bf16(af[i], bfr[j],
                                                                    acc[i][j], 0, 0, 0);
        __syncthreads();
    }
    const int gm = m0 + wr * 64;
    const int gn = n0 + wc * 64;
    float bcol[4];
#pragma unroll
    for (int j = 0; j < 4; ++j) bcol[j] = bias[gn + j * 16 + lrow];
#pragma unroll
    for (int i = 0; i < 4; ++i) {
#pragma unroll
        for (int r = 0; r < 4; ++r) {
            const int row = gm + i * 16 + lkg * 4 + r;
            const float vr = val[row];
            float2* orow = (float2*)(out + (size_t)row * N * 2);
#pragma unroll
            for (int j = 0; j < 4; ++j) {
                const int col = gn + j * 16 + lrow;
                float a = fmaxf(acc[i][j][r] + bcol[j], 0.f);
                orow[col] = make_float2(a, vr);
            }
        }
    }
}

extern "C" void kernel_launch(void* const* d_in, const int* in_sizes, int n_in,
                              void* d_out, int out_size, void* d_ws, size_t ws_size,
                              hipStream_t stream) {
    const float* x = (const float*)d_in[0];     // [B, DIN, 2]
    const float* W = (const float*)d_in[1];     // [DOUT, DIN]
    const float* b = (const float*)d_in[2];     // [DOUT]
    float* out = (float*)d_out;                 // [B, DOUT, 2]

    const int DOUT = in_sizes[2];
    const int DIN = in_sizes[1] / DOUT;
    const int B = in_sizes[0] / (2 * DIN);

    float* val = (float*)d_ws;
    const size_t aoff = 8192;
    const size_t abytes = (size_t)B * DIN * 2;
    const size_t wbytes = (size_t)DOUT * DIN * 2;
    const bool big = ws_size >= aoff + abytes + wbytes &&
                     (B % 128) == 0 && (DOUT % 128) == 0 && (DIN % 128) == 0;

    if (big) {
        uint4* abf = (uint4*)((char*)d_ws + aoff);
        uint4* wbf = (uint4*)((char*)d_ws + aoff + abytes);

        (void)hipMemsetAsync(val, 0, (size_t)B * sizeof(float), stream);

        const int osteps = DIN / 128;          // 16-step groups of octets
        int split = 1;
        for (int c : {16, 8, 4, 2}) { if (osteps % c == 0) { split = c; break; } }
        const int spb = osteps / split;

        dim3 gx(B / 16, split);
        convert_frag<true><<<gx, 256, 0, stream>>>(x, abf, val, DIN, spb);
        dim3 gw(DOUT / 16, split);
        convert_frag<false><<<gw, 256, 0, stream>>>(W, wbf, nullptr, DIN, spb);

        const int nwg = (DOUT / 128) * (B / 128);
        gemm_frag<<<nwg, 256, 0, stream>>>(abf, wbf, b, val, out, B, DOUT, DIN);
    } else {
        convert_x_stats<<<B, 256, 0, stream>>>((const float4*)x, nullptr, val, DIN);
        dim3 grid(DOUT / 128, B / 128);
        gemm_fallback<<<grid, 256, 0, stream>>>(x, W, b, val, out, B, DOUT, DIN);
    }
}

// Round 6
// 117.071 us; speedup vs baseline: 1.0838x; 1.0838x over previous
//
#include <hip/hip_runtime.h>
#include <stdint.h>

// ---------------------------------------------------------------------------
// AVNNType1Linear: out[b,o,0] = relu(sum_k x[b,k,0]*W[o,k] + bias[o])
//                  out[b,o,1] = (sum_k x[b,k,0] + sum_k x[b,k,1]) / (2*K)
// M=2048, N=4096, K=4096 fp32.
// r6 design: HYBRID GEMM. A = fragment-major bf16 loaded global->VGPR
// (double-buffered regs, L1-served reuse); B = row-major bf16 staged via
// global_load_lds DMA with the r3-verified 3-bit XOR swizzle, double-buffered
// LDS (32 KB -> 2 blocks/CU). Halves LDS-port traffic vs r4 (the measured
// wall: 2100cy LDS vs 1242cy MFMA per tile-pair).
// ---------------------------------------------------------------------------

typedef __bf16 bf16x8_t __attribute__((ext_vector_type(8)));
typedef float f32x4_t __attribute__((ext_vector_type(4)));
typedef __attribute__((address_space(1))) void gvoid_t;
typedef __attribute__((address_space(3))) void lvoid_t;

__device__ __forceinline__ uint32_t f32_to_bf16_rne(float f) {
    uint32_t u = __float_as_uint(f);
    return (u + 0x7fffu + ((u >> 16) & 1u)) >> 16;
}

// 3-bit XOR swizzle (verified conflict-free in r3/r4)
__device__ __forceinline__ uint32_t swz(uint32_t b) {
    return b ^ (((b >> 7) & 7u) << 4);
}

__device__ __forceinline__ bf16x8_t ds_read128(uint32_t addr) {
    bf16x8_t d;
    asm volatile("ds_read_b128 %0, %1" : "=&v"(d) : "v"(addr));
    return d;
}

// ---- kernel 1: x -> A-fragment-major bf16 + row stats (r5, verified) ----
// Fragment layout (16B granules): [strip=row/64][ks=k/32][rfrag=(row%64)/16]
//   [lane] with lane = (row%16) | (((k%32)/8)<<4), granule = 8 bf16.
__global__ __launch_bounds__(256) void convert_x_frag(
    const float* __restrict__ src, uint4* __restrict__ dst,
    float* __restrict__ val, int K, int spb) {
    const int t = threadIdx.x;
    const int rbase = blockIdx.x * 16;
    const int r16 = t & 15, og = t >> 4;          // og 0..15
    const int row = rbase + r16;
    const int ksn = K >> 5;
    const int strip = row >> 6, rfrag = (row >> 4) & 3;
    float s = 0.f;
    const int st0 = blockIdx.y * spb;
    for (int st = st0; st < st0 + spb; ++st) {
        const int o = og + st * 16;               // k-octet index
        const int k = o * 8;
        uint32_t pk[4];
        const float4* p = (const float4*)(src + ((size_t)row * K + k) * 2);
#pragma unroll
        for (int i = 0; i < 4; ++i) {
            float4 v = p[i];
            s += (v.x + v.y) + (v.z + v.w);
            pk[i] = f32_to_bf16_rne(v.x) | (f32_to_bf16_rne(v.z) << 16);
        }
        const int ks = o >> 2;
        const int ln = r16 | ((o & 3) << 4);
        dst[((size_t)(strip * ksn + ks) * 4 + rfrag) * 64 + ln] =
            make_uint4(pk[0], pk[1], pk[2], pk[3]);
    }
    s += __shfl_xor(s, 16, 64);
    s += __shfl_xor(s, 32, 64);
    __shared__ float red[4][16];
    if ((t & 48) == 0) red[t >> 6][r16] = s;
    __syncthreads();
    if (t < 16) {
        float p = red[0][t] + red[1][t] + red[2][t] + red[3][t];
        atomicAdd(&val[rbase + t], p / (float)(2 * K));
    }
}

// ---- kernel 2: W -> row-major bf16 (r4, verified) ----
__global__ __launch_bounds__(256) void convert_w(
    const float4* __restrict__ w4, uint2* __restrict__ wbf, int n4) {
    const int i = blockIdx.x * 256 + threadIdx.x;
    if (i < n4) {
        float4 v = w4[i];
        uint2 p;
        p.x = f32_to_bf16_rne(v.x) | (f32_to_bf16_rne(v.y) << 16);
        p.y = f32_to_bf16_rne(v.z) | (f32_to_bf16_rne(v.w) << 16);
        wbf[i] = p;
    }
}

// ---- kernel 3: hybrid 128x128 GEMM: A direct frags, B via LDS DMA ----
#define BKB 128              // BK bytes per B row (64 bf16)
#define NSLAB 16384          // 128 x 64 x 2B
#define LDS_BYTES (2 * NSLAB)   // 32 KiB

__global__ __launch_bounds__(256, 2) void gemm_hyb(
    const uint4* __restrict__ Af, const uint16_t* __restrict__ Wbf,
    const float* __restrict__ bias, const float* __restrict__ val,
    float* __restrict__ out, int M, int N, int K) {
    extern __shared__ char lds[];
    const uint32_t lds0 = (uint32_t)(uintptr_t)(lvoid_t*)lds;

    const int tid = threadIdx.x;
    const int wv = tid >> 6;
    const int lane = tid & 63;
    const int lrow = lane & 15, lkg = lane >> 4;
    const int nbx = N >> 7, nby = M >> 7;
    const int nwg = nbx * nby;

    // XCD-aware remap (r4-proven, bijective when nwg%8==0), y-fastest
    int wg = blockIdx.x;
    if ((nwg & 7) == 0) {
        const int cpx = nwg >> 3;
        wg = (wg & 7) * cpx + (wg >> 3);
    }
    const int y = wg % nby, x = wg / nby;
    const int m0 = y * 128, n0 = x * 128;
    const int wr = wv >> 1, wc = wv & 1;

    // B staging: linear LDS dest chunk c=l*256+tid holds swizzled tile byte
    uint32_t bsrc[4];
#pragma unroll
    for (int l = 0; l < 4; ++l) {
        uint32_t sb = swz((uint32_t)(l * 256 + tid) * 16u);
        bsrc[l] = (uint32_t)(n0 + (int)(sb >> 7)) * (uint32_t)(K * 2) + (sb & 127u);
    }
    // B swizzled read offsets (ks0; ks1 = ^64)
    uint32_t brd[4];
#pragma unroll
    for (int n = 0; n < 4; ++n)
        brd[n] = swz((uint32_t)(wc * 64 + n * 16 + lrow) * 128u + (uint32_t)(lkg * 16));

    // A fragment stream pointer for this wave (contiguous 8KB per K-64 tile)
    const int ksn = K >> 5;
    const bf16x8_t* awp = (const bf16x8_t*)Af +
        ((size_t)((m0 >> 6) + wr) * ksn * 4) * 64 + lane;

    f32x4_t acc[4][4];
#pragma unroll
    for (int i = 0; i < 4; ++i)
#pragma unroll
        for (int j = 0; j < 4; ++j) acc[i][j] = (f32x4_t){0.f, 0.f, 0.f, 0.f};

    const int NT = K >> 6;
    bf16x8_t A0[8], A1[8];

#define LOADA(Ad, tt)                                                         \
    {                                                                         \
        const bf16x8_t* ap = awp + (size_t)(tt) * 512;                        \
        _Pragma("unroll") for (int q = 0; q < 8; ++q) Ad[q] = ap[q * 64];     \
    }
#define STAGE_B(tt)                                                           \
    {                                                                         \
        const int slot = (tt) & 1;                                            \
        _Pragma("unroll") for (int l = 0; l < 4; ++l) {                       \
            const char* src = (const char*)Wbf + bsrc[l] + (size_t)(tt) * BKB;\
            char* dst = lds + slot * NSLAB + l * 4096 + wv * 1024;            \
            __builtin_amdgcn_global_load_lds((gvoid_t*)src, (lvoid_t*)dst,    \
                                             16, 0, 0);                       \
        }                                                                     \
    }
    // one K-64 tile using A-buffer Ac, prefetching into An
#define TILE(tt, Ac, An)                                                      \
    {                                                                         \
        const uint32_t lb = lds0 + ((tt) & 1) * NSLAB;                        \
        if ((tt) + 1 < NT) { STAGE_B((tt) + 1); LOADA(An, (tt) + 1); }        \
        bf16x8_t b0[4], b1[4];                                                \
        _Pragma("unroll") for (int n = 0; n < 4; ++n)                         \
            b0[n] = ds_read128(lb + brd[n]);                                  \
        _Pragma("unroll") for (int n = 0; n < 4; ++n)                         \
            b1[n] = ds_read128(lb + (brd[n] ^ 64u));                          \
        asm volatile("s_waitcnt lgkmcnt(4)" ::: "memory");                    \
        __builtin_amdgcn_sched_barrier(0);                                    \
        __builtin_amdgcn_s_setprio(1);                                        \
        _Pragma("unroll") for (int m = 0; m < 4; ++m)                         \
            _Pragma("unroll") for (int n = 0; n < 4; ++n)                     \
                acc[m][n] = __builtin_amdgcn_mfma_f32_16x16x32_bf16(          \
                    Ac[m], b0[n], acc[m][n], 0, 0, 0);                        \
        __builtin_amdgcn_s_setprio(0);                                        \
        asm volatile("s_waitcnt lgkmcnt(0)" ::: "memory");                    \
        __builtin_amdgcn_sched_barrier(0);                                    \
        __builtin_amdgcn_s_setprio(1);                                        \
        _Pragma("unroll") for (int m = 0; m < 4; ++m)                         \
            _Pragma("unroll") for (int n = 0; n < 4; ++n)                     \
                acc[m][n] = __builtin_amdgcn_mfma_f32_16x16x32_bf16(          \
                    Ac[4 + m], b1[n], acc[m][n], 0, 0, 0);                    \
        __builtin_amdgcn_s_setprio(0);                                        \
        if ((tt) + 1 < NT) {                                                  \
            asm volatile("s_waitcnt vmcnt(0)" ::: "memory");                  \
            __builtin_amdgcn_sched_barrier(0);                                \
            __builtin_amdgcn_s_barrier();                                     \
        }                                                                     \
    }

    // prologue
    STAGE_B(0);
    LOADA(A0, 0);
    asm volatile("s_waitcnt vmcnt(0)" ::: "memory");
    __builtin_amdgcn_sched_barrier(0);
    __builtin_amdgcn_s_barrier();

    for (int t = 0; t < NT; t += 2) {
        TILE(t, A0, A1);
        if (t + 1 < NT) TILE(t + 1, A1, A0);
    }
#undef LOADA
#undef STAGE_B
#undef TILE

    // ---------------- epilogue: bias + relu + val interleave ----------------
    const int gmb = m0 + wr * 64;
    const int gnb = n0 + wc * 64;
    float bcol[4];
#pragma unroll
    for (int n = 0; n < 4; ++n) bcol[n] = bias[gnb + n * 16 + lrow];
#pragma unroll
    for (int m = 0; m < 4; ++m) {
#pragma unroll
        for (int r = 0; r < 4; ++r) {
            const int row = gmb + m * 16 + lkg * 4 + r;
            const float vr = val[row];
            float2* orow = (float2*)(out + (size_t)row * N * 2);
#pragma unroll
            for (int n = 0; n < 4; ++n) {
                const int col = gnb + n * 16 + lrow;
                float a = fmaxf(acc[m][n][r] + bcol[n], 0.f);
                orow[col] = make_float2(a, vr);
            }
        }
    }
}

// ---- fallback kernels (small ws): r0 path, known-correct ----
__global__ __launch_bounds__(256) void convert_x_stats(
    const float4* __restrict__ x4, uint32_t* __restrict__ abf,
    float* __restrict__ val, int din) {
    const int row = blockIdx.x;
    const int t = threadIdx.x;
    const int f4pr = din >> 1;
    const float4* xr = x4 + (size_t)row * f4pr;
    float s = 0.f;
    for (int i = t; i < f4pr; i += 256) {
        float4 v = xr[i];
        s += (v.x + v.y) + (v.z + v.w);
    }
#pragma unroll
    for (int off = 32; off; off >>= 1) s += __shfl_down(s, off, 64);
    __shared__ float red[4];
    if ((t & 63) == 0) red[t >> 6] = s;
    __syncthreads();
    if (t == 0) val[row] = (red[0] + red[1] + red[2] + red[3]) / (float)(2 * din);
}

__global__ __launch_bounds__(256) void gemm_fallback(
    const float* __restrict__ xf, const float* __restrict__ Wf,
    const float* __restrict__ bias, const float* __restrict__ val,
    float* __restrict__ out, int M, int N, int K) {
    __shared__ uint16_t lA[128 * 32];
    __shared__ uint16_t lB[128 * 32];
    const int tid = threadIdx.x;
    const int wv = tid >> 6;
    const int lane = tid & 63;
    const int lrow = lane & 15;
    const int lkg = lane >> 4;
    const int m0 = blockIdx.y * 128;
    const int n0 = blockIdx.x * 128;
    const int wr = wv >> 1, wc = wv & 1;
    f32x4_t acc[4][4];
#pragma unroll
    for (int i = 0; i < 4; ++i)
#pragma unroll
        for (int j = 0; j < 4; ++j) acc[i][j] = (f32x4_t){0.f, 0.f, 0.f, 0.f};
    for (int k0 = 0; k0 < K; k0 += 32) {
        float4 va[8];
        float4 vb[4];
#pragma unroll
        for (int i = 0; i < 8; ++i) {
            const int p = i * 256 + tid;
            const int row = p >> 4, pc = p & 15;
            va[i] = *(const float4*)(xf + ((size_t)(m0 + row) * K + k0 + pc * 2) * 2);
        }
#pragma unroll
        for (int i = 0; i < 4; ++i) {
            const int q = i * 256 + tid;
            const int row = q >> 3, qc = q & 7;
            vb[i] = *(const float4*)(Wf + (size_t)(n0 + row) * K + k0 + qc * 4);
        }
        __syncthreads();
#pragma unroll
        for (int i = 0; i < 8; ++i) {
            const int p = i * 256 + tid;
            const int row = p >> 4, pc = p & 15;
            *(uint32_t*)&lA[row * 32 + pc * 2] =
                f32_to_bf16_rne(va[i].x) | (f32_to_bf16_rne(va[i].z) << 16);
        }
#pragma unroll
        for (int i = 0; i < 4; ++i) {
            const int q = i * 256 + tid;
            const int row = q >> 3, qc = q & 7;
            uint2 pk;
            pk.x = f32_to_bf16_rne(vb[i].x) | (f32_to_bf16_rne(vb[i].y) << 16);
            pk.y = f32_to_bf16_rne(vb[i].z) | (f32_to_bf16_rne(vb[i].w) << 16);
            *(uint2*)&lB[row * 32 + qc * 4] = pk;
        }
        __syncthreads();
        bf16x8_t af[4], bfr[4];
#pragma unroll
        for (int i = 0; i < 4; ++i)
            af[i] = *(const bf16x8_t*)&lA[(wr * 64 + i * 16 + lrow) * 32 + lkg * 8];
#pragma unroll
        for (int j = 0; j < 4; ++j)
            bfr[j] = *(const bf16x8_t*)&lB[(wc * 64 + j * 16 + lrow) * 32 + lkg * 8];
#pragma unroll
        for (int i = 0; i < 4; ++i)
#pragma unroll
            for (int j = 0; j < 4; ++j)
                acc[i][j] = __builtin_amdgcn_mfma_f32_16x16x32_bf16(af[i], bfr[j],
                                                                    acc[i][j], 0, 0, 0);
        __syncthreads();
    }
    const int gm = m0 + wr * 64;
    const int gn = n0 + wc * 64;
    float bcol[4];
#pragma unroll
    for (int j = 0; j < 4; ++j) bcol[j] = bias[gn + j * 16 + lrow];
#pragma unroll
    for (int i = 0; i < 4; ++i) {
#pragma unroll
        for (int r = 0; r < 4; ++r) {
            const int row = gm + i * 16 + lkg * 4 + r;
            const float vr = val[row];
            float2* orow = (float2*)(out + (size_t)row * N * 2);
#pragma unroll
            for (int j = 0; j < 4; ++j) {
                const int col = gn + j * 16 + lrow;
                float a = fmaxf(acc[i][j][r] + bcol[j], 0.f);
                orow[col] = make_float2(a, vr);
            }
        }
    }
}

extern "C" void kernel_launch(void* const* d_in, const int* in_sizes, int n_in,
                              void* d_out, int out_size, void* d_ws, size_t ws_size,
                              hipStream_t stream) {
    const float* x = (const float*)d_in[0];     // [B, DIN, 2]
    const float* W = (const float*)d_in[1];     // [DOUT, DIN]
    const float* b = (const float*)d_in[2];     // [DOUT]
    float* out = (float*)d_out;                 // [B, DOUT, 2]

    const int DOUT = in_sizes[2];
    const int DIN = in_sizes[1] / DOUT;
    const int B = in_sizes[0] / (2 * DIN);

    float* val = (float*)d_ws;
    const size_t aoff = 8192;
    const size_t abytes = (size_t)B * DIN * 2;
    const size_t wbytes = (size_t)DOUT * DIN * 2;
    const bool big = ws_size >= aoff + abytes + wbytes &&
                     (B % 128) == 0 && (DOUT % 128) == 0 && (DIN % 128) == 0;

    if (big) {
        uint4* abf = (uint4*)((char*)d_ws + aoff);
        uint32_t* wbf = (uint32_t*)((char*)d_ws + aoff + abytes);

        (void)hipMemsetAsync(val, 0, (size_t)B * sizeof(float), stream);

        const int osteps = DIN / 128;
        int split = 1;
        for (int c : {16, 8, 4, 2}) { if (osteps % c == 0) { split = c; break; } }
        const int spb = osteps / split;
        dim3 gx(B / 16, split);
        convert_x_frag<<<gx, 256, 0, stream>>>(x, abf, val, DIN, spb);

        const int n4 = DOUT * DIN / 4;
        convert_w<<<(n4 + 255) / 256, 256, 0, stream>>>((const float4*)W, (uint2*)wbf, n4);

        (void)hipFuncSetAttribute((const void*)gemm_hyb,
                                  hipFuncAttributeMaxDynamicSharedMemorySize, LDS_BYTES);
        const int nwg = (DOUT / 128) * (B / 128);
        gemm_hyb<<<nwg, 256, LDS_BYTES, stream>>>(abf, (const uint16_t*)wbf,
                                                  b, val, out, B, DOUT, DIN);
    } else {
        convert_x_stats<<<B, 256, 0, stream>>>((const float4*)x, nullptr, val, DIN);
        dim3 grid(DOUT / 128, B / 128);
        gemm_fallback<<<grid, 256, 0, stream>>>(x, W, b, val, out, B, DOUT, DIN);
    }
}

// Round 7
// 114.651 us; speedup vs baseline: 1.1067x; 1.0211x over previous
//
#include <hip/hip_runtime.h>
#include <stdint.h>

// ---------------------------------------------------------------------------
// AVNNType1Linear: out[b,o,0] = relu(sum_k x[b,k,0]*W[o,k] + bias[o])
//                  out[b,o,1] = (sum_k x[b,k,0] + sum_k x[b,k,1]) / (2*K)
// M=2048, N=4096, K=4096 fp32.
// r7: hybrid GEMM, A-dbuf FORCED via inline-asm global_load_dwordx4
// ("=&v" outputs cannot be sunk/deleted), B via 3-slot global_load_lds
// rotation with counted vmcnt(4) (never drains in steady state).
// LDS-port traffic = B only (~1030cy/tile-pair) < MFMA (1242cy).
// ---------------------------------------------------------------------------

typedef __bf16 bf16x8_t __attribute__((ext_vector_type(8)));
typedef float f32x4_t __attribute__((ext_vector_type(4)));
typedef __attribute__((address_space(1))) void gvoid_t;
typedef __attribute__((address_space(3))) void lvoid_t;

__device__ __forceinline__ uint32_t f32_to_bf16_rne(float f) {
    uint32_t u = __float_as_uint(f);
    return (u + 0x7fffu + ((u >> 16) & 1u)) >> 16;
}

// 3-bit XOR swizzle (verified conflict-free in r3/r4)
__device__ __forceinline__ uint32_t swz(uint32_t b) {
    return b ^ (((b >> 7) & 7u) << 4);
}

__device__ __forceinline__ bf16x8_t ds_read128(uint32_t addr) {
    bf16x8_t d;
    asm volatile("ds_read_b128 %0, %1" : "=&v"(d) : "v"(addr));
    return d;
}

// forced global->VGPR 16B load; volatile asm keeps issue order, "=&v" forces
// a real register destination (compiler cannot sink/delete the prefetch).
__device__ __forceinline__ bf16x8_t gload16(const void* p) {
    bf16x8_t d;
    asm volatile("global_load_dwordx4 %0, %1, off" : "=&v"(d) : "v"(p));
    return d;
}

// ---- kernel 1: x -> A-fragment-major bf16 + row stats (r5/r6, verified) ----
// Fragment layout (16B granules): [strip=row/64][ks=k/32][rfrag=(row%64)/16]
//   [lane] with lane = (row%16) | (((k%32)/8)<<4), granule = 8 bf16.
__global__ __launch_bounds__(256) void convert_x_frag(
    const float* __restrict__ src, uint4* __restrict__ dst,
    float* __restrict__ val, int K, int spb) {
    const int t = threadIdx.x;
    const int rbase = blockIdx.x * 16;
    const int r16 = t & 15, og = t >> 4;          // og 0..15
    const int row = rbase + r16;
    const int ksn = K >> 5;
    const int strip = row >> 6, rfrag = (row >> 4) & 3;
    float s = 0.f;
    const int st0 = blockIdx.y * spb;
    for (int st = st0; st < st0 + spb; ++st) {
        const int o = og + st * 16;               // k-octet index
        const int k = o * 8;
        uint32_t pk[4];
        const float4* p = (const float4*)(src + ((size_t)row * K + k) * 2);
#pragma unroll
        for (int i = 0; i < 4; ++i) {
            float4 v = p[i];
            s += (v.x + v.y) + (v.z + v.w);
            pk[i] = f32_to_bf16_rne(v.x) | (f32_to_bf16_rne(v.z) << 16);
        }
        const int ks = o >> 2;
        const int ln = r16 | ((o & 3) << 4);
        dst[((size_t)(strip * ksn + ks) * 4 + rfrag) * 64 + ln] =
            make_uint4(pk[0], pk[1], pk[2], pk[3]);
    }
    s += __shfl_xor(s, 16, 64);
    s += __shfl_xor(s, 32, 64);
    __shared__ float red[4][16];
    if ((t & 48) == 0) red[t >> 6][r16] = s;
    __syncthreads();
    if (t < 16) {
        float p = red[0][t] + red[1][t] + red[2][t] + red[3][t];
        atomicAdd(&val[rbase + t], p / (float)(2 * K));
    }
}

// ---- kernel 2: W -> row-major bf16 (r4, verified) ----
__global__ __launch_bounds__(256) void convert_w(
    const float4* __restrict__ w4, uint2* __restrict__ wbf, int n4) {
    const int i = blockIdx.x * 256 + threadIdx.x;
    if (i < n4) {
        float4 v = w4[i];
        uint2 p;
        p.x = f32_to_bf16_rne(v.x) | (f32_to_bf16_rne(v.y) << 16);
        p.y = f32_to_bf16_rne(v.z) | (f32_to_bf16_rne(v.w) << 16);
        wbf[i] = p;
    }
}

// ---- kernel 3: hybrid 128x128 GEMM: A asm-forced reg dbuf, B 3-slot LDS ----
#define BKB 128              // BK bytes per B row (64 bf16)
#define NSLAB 16384          // 128 x 64 x 2B
#define LDS_BYTES (3 * NSLAB)   // 48 KiB -> 2 blocks/CU (VGPR-bound)

__global__ __launch_bounds__(256, 2) void gemm_hyb(
    const uint4* __restrict__ Af, const uint16_t* __restrict__ Wbf,
    const float* __restrict__ bias, const float* __restrict__ val,
    float* __restrict__ out, int M, int N, int K) {
    extern __shared__ char lds[];
    const uint32_t lds0 = (uint32_t)(uintptr_t)(lvoid_t*)lds;

    const int tid = threadIdx.x;
    const int wv = tid >> 6;
    const int lane = tid & 63;
    const int lrow = lane & 15, lkg = lane >> 4;
    const int m0 = blockIdx.y * 128;
    const int n0 = blockIdx.x * 128;
    const int wr = wv >> 1, wc = wv & 1;

    // B staging: linear LDS dest chunk c=l*256+tid holds swizzled tile byte
    uint32_t bsrc[4];
#pragma unroll
    for (int l = 0; l < 4; ++l) {
        uint32_t sb = swz((uint32_t)(l * 256 + tid) * 16u);
        bsrc[l] = (uint32_t)(n0 + (int)(sb >> 7)) * (uint32_t)(K * 2) + (sb & 127u);
    }
    // B swizzled read offsets (ks0; ks1 = ^64)
    uint32_t brd[4];
#pragma unroll
    for (int n = 0; n < 4; ++n)
        brd[n] = swz((uint32_t)(wc * 64 + n * 16 + lrow) * 128u + (uint32_t)(lkg * 16));

    // A fragment stream base for this wave (contiguous 8KB per K-64 tile)
    const int ksn = K >> 5;
    const char* abase = (const char*)Af +
        (((size_t)((m0 >> 6) + wr) * ksn * 4) * 64 + lane) * 16;

    f32x4_t acc[4][4];
#pragma unroll
    for (int i = 0; i < 4; ++i)
#pragma unroll
        for (int j = 0; j < 4; ++j) acc[i][j] = (f32x4_t){0.f, 0.f, 0.f, 0.f};

    const int NT = K >> 6;
    bf16x8_t A0[8], A1[8];

#define LOADA(Ad, tt)                                                         \
    {                                                                         \
        const char* ap = abase + (size_t)(tt) * 8192;                         \
        _Pragma("unroll") for (int q = 0; q < 8; ++q)                         \
            Ad[q] = gload16(ap + q * 1024);                                   \
    }
#define STAGE_B(tt)                                                           \
    {                                                                         \
        const int slot = (tt) % 3;                                            \
        _Pragma("unroll") for (int l = 0; l < 4; ++l) {                       \
            const char* src = (const char*)Wbf + bsrc[l] + (size_t)(tt) * BKB;\
            char* dst = lds + slot * NSLAB + l * 4096 + wv * 1024;            \
            __builtin_amdgcn_global_load_lds((gvoid_t*)src, (lvoid_t*)dst,    \
                                             16, 0, 0);                       \
        }                                                                     \
    }
    // one K-64 tile using A-buffer Ac, prefetching A(t+1) into An
#define TILE(tt, Ac, An)                                                      \
    {                                                                         \
        if ((tt) + 1 < NT) LOADA(An, (tt) + 1);                               \
        if ((tt) + 2 < NT) STAGE_B((tt) + 2);                                 \
        const uint32_t lb = lds0 + ((tt) % 3) * NSLAB;                        \
        bf16x8_t b0[4], b1[4];                                                \
        _Pragma("unroll") for (int n = 0; n < 4; ++n)                         \
            b0[n] = ds_read128(lb + brd[n]);                                  \
        _Pragma("unroll") for (int n = 0; n < 4; ++n)                         \
            b1[n] = ds_read128(lb + (brd[n] ^ 64u));                          \
        asm volatile("s_waitcnt lgkmcnt(4)" ::: "memory");                    \
        __builtin_amdgcn_sched_barrier(0);                                    \
        __builtin_amdgcn_s_setprio(1);                                        \
        _Pragma("unroll") for (int m = 0; m < 4; ++m)                         \
            _Pragma("unroll") for (int n = 0; n < 4; ++n)                     \
                acc[m][n] = __builtin_amdgcn_mfma_f32_16x16x32_bf16(          \
                    Ac[m], b0[n], acc[m][n], 0, 0, 0);                        \
        __builtin_amdgcn_s_setprio(0);                                        \
        asm volatile("s_waitcnt lgkmcnt(0)" ::: "memory");                    \
        __builtin_amdgcn_sched_barrier(0);                                    \
        __builtin_amdgcn_s_setprio(1);                                        \
        _Pragma("unroll") for (int m = 0; m < 4; ++m)                         \
            _Pragma("unroll") for (int n = 0; n < 4; ++n)                     \
                acc[m][n] = __builtin_amdgcn_mfma_f32_16x16x32_bf16(          \
                    Ac[4 + m], b1[n], acc[m][n], 0, 0, 0);                    \
        __builtin_amdgcn_s_setprio(0);                                        \
        if ((tt) + 1 < NT) {                                                  \
            if ((tt) + 2 < NT) {                                              \
                asm volatile("s_waitcnt vmcnt(4)" ::: "memory");              \
            } else {                                                          \
                asm volatile("s_waitcnt vmcnt(0)" ::: "memory");              \
            }                                                                 \
            __builtin_amdgcn_sched_barrier(0);                                \
            __builtin_amdgcn_s_barrier();                                     \
        }                                                                     \
    }

    // prologue: B0, A0, B1 in flight; wait {B0, A0} (B1 stays outstanding)
    STAGE_B(0);
    LOADA(A0, 0);
    if (NT > 1) {
        STAGE_B(1);
        asm volatile("s_waitcnt vmcnt(4)" ::: "memory");
    } else {
        asm volatile("s_waitcnt vmcnt(0)" ::: "memory");
    }
    __builtin_amdgcn_sched_barrier(0);
    __builtin_amdgcn_s_barrier();

    for (int t = 0; t < NT; t += 2) {
        TILE(t, A0, A1);
        if (t + 1 < NT) TILE(t + 1, A1, A0);
    }
#undef LOADA
#undef STAGE_B
#undef TILE

    // ---------------- epilogue: bias + relu + val interleave ----------------
    const int gmb = m0 + wr * 64;
    const int gnb = n0 + wc * 64;
    float bcol[4];
#pragma unroll
    for (int n = 0; n < 4; ++n) bcol[n] = bias[gnb + n * 16 + lrow];
#pragma unroll
    for (int m = 0; m < 4; ++m) {
#pragma unroll
        for (int r = 0; r < 4; ++r) {
            const int row = gmb + m * 16 + lkg * 4 + r;
            const float vr = val[row];
            float2* orow = (float2*)(out + (size_t)row * N * 2);
#pragma unroll
            for (int n = 0; n < 4; ++n) {
                const int col = gnb + n * 16 + lrow;
                float a = fmaxf(acc[m][n][r] + bcol[n], 0.f);
                orow[col] = make_float2(a, vr);
            }
        }
    }
}

// ---- fallback kernels (small ws): r0 path, known-correct ----
__global__ __launch_bounds__(256) void convert_x_stats(
    const float4* __restrict__ x4, uint32_t* __restrict__ abf,
    float* __restrict__ val, int din) {
    const int row = blockIdx.x;
    const int t = threadIdx.x;
    const int f4pr = din >> 1;
    const float4* xr = x4 + (size_t)row * f4pr;
    float s = 0.f;
    for (int i = t; i < f4pr; i += 256) {
        float4 v = xr[i];
        s += (v.x + v.y) + (v.z + v.w);
    }
#pragma unroll
    for (int off = 32; off; off >>= 1) s += __shfl_down(s, off, 64);
    __shared__ float red[4];
    if ((t & 63) == 0) red[t >> 6] = s;
    __syncthreads();
    if (t == 0) val[row] = (red[0] + red[1] + red[2] + red[3]) / (float)(2 * din);
}

__global__ __launch_bounds__(256) void gemm_fallback(
    const float* __restrict__ xf, const float* __restrict__ Wf,
    const float* __restrict__ bias, const float* __restrict__ val,
    float* __restrict__ out, int M, int N, int K) {
    __shared__ uint16_t lA[128 * 32];
    __shared__ uint16_t lB[128 * 32];
    const int tid = threadIdx.x;
    const int wv = tid >> 6;
    const int lane = tid & 63;
    const int lrow = lane & 15;
    const int lkg = lane >> 4;
    const int m0 = blockIdx.y * 128;
    const int n0 = blockIdx.x * 128;
    const int wr = wv >> 1, wc = wv & 1;
    f32x4_t acc[4][4];
#pragma unroll
    for (int i = 0; i < 4; ++i)
#pragma unroll
        for (int j = 0; j < 4; ++j) acc[i][j] = (f32x4_t){0.f, 0.f, 0.f, 0.f};
    for (int k0 = 0; k0 < K; k0 += 32) {
        float4 va[8];
        float4 vb[4];
#pragma unroll
        for (int i = 0; i < 8; ++i) {
            const int p = i * 256 + tid;
            const int row = p >> 4, pc = p & 15;
            va[i] = *(const float4*)(xf + ((size_t)(m0 + row) * K + k0 + pc * 2) * 2);
        }
#pragma unroll
        for (int i = 0; i < 4; ++i) {
            const int q = i * 256 + tid;
            const int row = q >> 3, qc = q & 7;
            vb[i] = *(const float4*)(Wf + (size_t)(n0 + row) * K + k0 + qc * 4);
        }
        __syncthreads();
#pragma unroll
        for (int i = 0; i < 8; ++i) {
            const int p = i * 256 + tid;
            const int row = p >> 4, pc = p & 15;
            *(uint32_t*)&lA[row * 32 + pc * 2] =
                f32_to_bf16_rne(va[i].x) | (f32_to_bf16_rne(va[i].z) << 16);
        }
#pragma unroll
        for (int i = 0; i < 4; ++i) {
            const int q = i * 256 + tid;
            const int row = q >> 3, qc = q & 7;
            uint2 pk;
            pk.x = f32_to_bf16_rne(vb[i].x) | (f32_to_bf16_rne(vb[i].y) << 16);
            pk.y = f32_to_bf16_rne(vb[i].z) | (f32_to_bf16_rne(vb[i].w) << 16);
            *(uint2*)&lB[row * 32 + qc * 4] = pk;
        }
        __syncthreads();
        bf16x8_t af[4], bfr[4];
#pragma unroll
        for (int i = 0; i < 4; ++i)
            af[i] = *(const bf16x8_t*)&lA[(wr * 64 + i * 16 + lrow) * 32 + lkg * 8];
#pragma unroll
        for (int j = 0; j < 4; ++j)
            bfr[j] = *(const bf16x8_t*)&lB[(wc * 64 + j * 16 + lrow) * 32 + lkg * 8];
#pragma unroll
        for (int i = 0; i < 4; ++i)
#pragma unroll
            for (int j = 0; j < 4; ++j)
                acc[i][j] = __builtin_amdgcn_mfma_f32_16x16x32_bf16(af[i], bfr[j],
                                                                    acc[i][j], 0, 0, 0);
        __syncthreads();
    }
    const int gm = m0 + wr * 64;
    const int gn = n0 + wc * 64;
    float bcol[4];
#pragma unroll
    for (int j = 0; j < 4; ++j) bcol[j] = bias[gn + j * 16 + lrow];
#pragma unroll
    for (int i = 0; i < 4; ++i) {
#pragma unroll
        for (int r = 0; r < 4; ++r) {
            const int row = gm + i * 16 + lkg * 4 + r;
            const float vr = val[row];
            float2* orow = (float2*)(out + (size_t)row * N * 2);
#pragma unroll
            for (int j = 0; j < 4; ++j) {
                const int col = gn + j * 16 + lrow;
                float a = fmaxf(acc[i][j][r] + bcol[j], 0.f);
                orow[col] = make_float2(a, vr);
            }
        }
    }
}

extern "C" void kernel_launch(void* const* d_in, const int* in_sizes, int n_in,
                              void* d_out, int out_size, void* d_ws, size_t ws_size,
                              hipStream_t stream) {
    const float* x = (const float*)d_in[0];     // [B, DIN, 2]
    const float* W = (const float*)d_in[1];     // [DOUT, DIN]
    const float* b = (const float*)d_in[2];     // [DOUT]
    float* out = (float*)d_out;                 // [B, DOUT, 2]

    const int DOUT = in_sizes[2];
    const int DIN = in_sizes[1] / DOUT;
    const int B = in_sizes[0] / (2 * DIN);

    float* val = (float*)d_ws;
    const size_t aoff = 8192;
    const size_t abytes = (size_t)B * DIN * 2;
    const size_t wbytes = (size_t)DOUT * DIN * 2;
    const bool big = ws_size >= aoff + abytes + wbytes &&
                     (B % 128) == 0 && (DOUT % 128) == 0 && (DIN % 128) == 0;

    if (big) {
        uint4* abf = (uint4*)((char*)d_ws + aoff);
        uint32_t* wbf = (uint32_t*)((char*)d_ws + aoff + abytes);

        (void)hipMemsetAsync(val, 0, (size_t)B * sizeof(float), stream);

        const int osteps = DIN / 128;
        int split = 1;
        for (int c : {16, 8, 4, 2}) { if (osteps % c == 0) { split = c; break; } }
        const int spb = osteps / split;
        dim3 gx(B / 16, split);
        convert_x_frag<<<gx, 256, 0, stream>>>(x, abf, val, DIN, spb);

        const int n4 = DOUT * DIN / 4;
        convert_w<<<(n4 + 255) / 256, 256, 0, stream>>>((const float4*)W, (uint2*)wbf, n4);

        (void)hipFuncSetAttribute((const void*)gemm_hyb,
                                  hipFuncAttributeMaxDynamicSharedMemorySize, LDS_BYTES);
        dim3 grid(DOUT / 128, B / 128);
        gemm_hyb<<<grid, 256, LDS_BYTES, stream>>>(abf, (const uint16_t*)wbf,
                                                   b, val, out, B, DOUT, DIN);
    } else {
        convert_x_stats<<<B, 256, 0, stream>>>((const float4*)x, nullptr, val, DIN);
        dim3 grid(DOUT / 128, B / 128);
        gemm_fallback<<<grid, 256, 0, stream>>>(x, W, b, val, out, B, DOUT, DIN);
    }
}

// Round 8
// 114.572 us; speedup vs baseline: 1.1074x; 1.0007x over previous
//
#include <hip/hip_runtime.h>
#include <stdint.h>

// ---------------------------------------------------------------------------
// AVNNType1Linear: out[b,o,0] = relu(sum_k x[b,k,0]*W[o,k] + bias[o])
//                  out[b,o,1] = (sum_k x[b,k,0] + sum_k x[b,k,1]) / (2*K)
// M=2048, N=4096, K=4096 fp32.
// r8: hybrid GEMM with 2-TILE-DEEP A prefetch. A = fragment-major bf16,
// asm-forced global->VGPR triple buffer; B = 3-slot global_load_lds rotation.
// End-of-tile wait = vmcnt(12): completes {A(t+1),B(t+1)}, leaves
// {A(t+2),B(t+2)} in flight (2 tile bodies of latency slack).
// ---------------------------------------------------------------------------

typedef __bf16 bf16x8_t __attribute__((ext_vector_type(8)));
typedef float f32x4_t __attribute__((ext_vector_type(4)));
typedef __attribute__((address_space(1))) void gvoid_t;
typedef __attribute__((address_space(3))) void lvoid_t;

__device__ __forceinline__ uint32_t f32_to_bf16_rne(float f) {
    uint32_t u = __float_as_uint(f);
    return (u + 0x7fffu + ((u >> 16) & 1u)) >> 16;
}

// 3-bit XOR swizzle (verified conflict-free in r3/r4)
__device__ __forceinline__ uint32_t swz(uint32_t b) {
    return b ^ (((b >> 7) & 7u) << 4);
}

__device__ __forceinline__ bf16x8_t ds_read128(uint32_t addr) {
    bf16x8_t d;
    asm volatile("ds_read_b128 %0, %1" : "=&v"(d) : "v"(addr));
    return d;
}

// forced global->VGPR 16B load; volatile asm keeps issue order, "=&v" forces
// a real register destination (compiler cannot sink/delete the prefetch).
__device__ __forceinline__ bf16x8_t gload16(const void* p) {
    bf16x8_t d;
    asm volatile("global_load_dwordx4 %0, %1, off" : "=&v"(d) : "v"(p));
    return d;
}

// ---- kernel 1: x -> A-fragment-major bf16 + row stats (r5-r7, verified) ----
// Fragment layout (16B granules): [strip=row/64][ks=k/32][rfrag=(row%64)/16]
//   [lane] with lane = (row%16) | (((k%32)/8)<<4), granule = 8 bf16.
__global__ __launch_bounds__(256) void convert_x_frag(
    const float* __restrict__ src, uint4* __restrict__ dst,
    float* __restrict__ val, int K, int spb) {
    const int t = threadIdx.x;
    const int rbase = blockIdx.x * 16;
    const int r16 = t & 15, og = t >> 4;          // og 0..15
    const int row = rbase + r16;
    const int ksn = K >> 5;
    const int strip = row >> 6, rfrag = (row >> 4) & 3;
    float s = 0.f;
    const int st0 = blockIdx.y * spb;
    for (int st = st0; st < st0 + spb; ++st) {
        const int o = og + st * 16;               // k-octet index
        const int k = o * 8;
        uint32_t pk[4];
        const float4* p = (const float4*)(src + ((size_t)row * K + k) * 2);
#pragma unroll
        for (int i = 0; i < 4; ++i) {
            float4 v = p[i];
            s += (v.x + v.y) + (v.z + v.w);
            pk[i] = f32_to_bf16_rne(v.x) | (f32_to_bf16_rne(v.z) << 16);
        }
        const int ks = o >> 2;
        const int ln = r16 | ((o & 3) << 4);
        dst[((size_t)(strip * ksn + ks) * 4 + rfrag) * 64 + ln] =
            make_uint4(pk[0], pk[1], pk[2], pk[3]);
    }
    s += __shfl_xor(s, 16, 64);
    s += __shfl_xor(s, 32, 64);
    __shared__ float red[4][16];
    if ((t & 48) == 0) red[t >> 6][r16] = s;
    __syncthreads();
    if (t < 16) {
        float p = red[0][t] + red[1][t] + red[2][t] + red[3][t];
        atomicAdd(&val[rbase + t], p / (float)(2 * K));
    }
}

// ---- kernel 2: W -> row-major bf16 (r4, verified) ----
__global__ __launch_bounds__(256) void convert_w(
    const float4* __restrict__ w4, uint2* __restrict__ wbf, int n4) {
    const int i = blockIdx.x * 256 + threadIdx.x;
    if (i < n4) {
        float4 v = w4[i];
        uint2 p;
        p.x = f32_to_bf16_rne(v.x) | (f32_to_bf16_rne(v.y) << 16);
        p.y = f32_to_bf16_rne(v.z) | (f32_to_bf16_rne(v.w) << 16);
        wbf[i] = p;
    }
}

// ---- kernel 3: hybrid 128x128 GEMM: A 3-buf asm regs, B 3-slot LDS ----
#define BKB 128              // BK bytes per B row (64 bf16)
#define NSLAB 16384          // 128 x 64 x 2B
#define LDS_BYTES (3 * NSLAB)   // 48 KiB

__global__ __launch_bounds__(256, 2) void gemm_hyb(
    const uint4* __restrict__ Af, const uint16_t* __restrict__ Wbf,
    const float* __restrict__ bias, const float* __restrict__ val,
    float* __restrict__ out, int M, int N, int K) {
    extern __shared__ char lds[];
    const uint32_t lds0 = (uint32_t)(uintptr_t)(lvoid_t*)lds;

    const int tid = threadIdx.x;
    const int wv = tid >> 6;
    const int lane = tid & 63;
    const int lrow = lane & 15, lkg = lane >> 4;
    const int m0 = blockIdx.y * 128;
    const int n0 = blockIdx.x * 128;
    const int wr = wv >> 1, wc = wv & 1;

    // B staging: linear LDS dest chunk c=l*256+tid holds swizzled tile byte
    uint32_t bsrc[4];
#pragma unroll
    for (int l = 0; l < 4; ++l) {
        uint32_t sb = swz((uint32_t)(l * 256 + tid) * 16u);
        bsrc[l] = (uint32_t)(n0 + (int)(sb >> 7)) * (uint32_t)(K * 2) + (sb & 127u);
    }
    // B swizzled read offsets (ks0; ks1 = ^64)
    uint32_t brd[4];
#pragma unroll
    for (int n = 0; n < 4; ++n)
        brd[n] = swz((uint32_t)(wc * 64 + n * 16 + lrow) * 128u + (uint32_t)(lkg * 16));

    // A fragment stream base for this wave (contiguous 8KB per K-64 tile)
    const int ksn = K >> 5;
    const char* abase = (const char*)Af +
        (((size_t)((m0 >> 6) + wr) * ksn * 4) * 64 + lane) * 16;

    f32x4_t acc[4][4];
#pragma unroll
    for (int i = 0; i < 4; ++i)
#pragma unroll
        for (int j = 0; j < 4; ++j) acc[i][j] = (f32x4_t){0.f, 0.f, 0.f, 0.f};

    const int NT = K >> 6;
    bf16x8_t A0[8], A1[8], A2[8];

#define LOADA(Ad, tt)                                                         \
    {                                                                         \
        const char* ap = abase + (size_t)(tt) * 8192;                         \
        _Pragma("unroll") for (int q = 0; q < 8; ++q)                         \
            Ad[q] = gload16(ap + q * 1024);                                   \
    }
#define STAGE_B(tt)                                                           \
    {                                                                         \
        const int slot = (tt) % 3;                                            \
        _Pragma("unroll") for (int l = 0; l < 4; ++l) {                       \
            const char* src = (const char*)Wbf + bsrc[l] + (size_t)(tt) * BKB;\
            char* dst = lds + slot * NSLAB + l * 4096 + wv * 1024;            \
            __builtin_amdgcn_global_load_lds((gvoid_t*)src, (lvoid_t*)dst,    \
                                             16, 0, 0);                       \
        }                                                                     \
    }
    // one K-64 tile using A-buffer Ac, prefetching A/B for tile tt+2
#define TILE(tt, Ac, An)                                                      \
    {                                                                         \
        const uint32_t lb = lds0 + ((tt) % 3) * NSLAB;                        \
        bf16x8_t b0[4], b1[4];                                                \
        _Pragma("unroll") for (int n = 0; n < 4; ++n)                         \
            b0[n] = ds_read128(lb + brd[n]);                                  \
        _Pragma("unroll") for (int n = 0; n < 4; ++n)                         \
            b1[n] = ds_read128(lb + (brd[n] ^ 64u));                          \
        if ((tt) + 2 < NT) { LOADA(An, (tt) + 2); STAGE_B((tt) + 2); }        \
        asm volatile("s_waitcnt lgkmcnt(4)" ::: "memory");                    \
        __builtin_amdgcn_sched_barrier(0);                                    \
        __builtin_amdgcn_s_setprio(1);                                        \
        _Pragma("unroll") for (int m = 0; m < 4; ++m)                         \
            _Pragma("unroll") for (int n = 0; n < 4; ++n)                     \
                acc[m][n] = __builtin_amdgcn_mfma_f32_16x16x32_bf16(          \
                    Ac[m], b0[n], acc[m][n], 0, 0, 0);                        \
        __builtin_amdgcn_s_setprio(0);                                        \
        asm volatile("s_waitcnt lgkmcnt(0)" ::: "memory");                    \
        __builtin_amdgcn_sched_barrier(0);                                    \
        __builtin_amdgcn_s_setprio(1);                                        \
        _Pragma("unroll") for (int m = 0; m < 4; ++m)                         \
            _Pragma("unroll") for (int n = 0; n < 4; ++n)                     \
                acc[m][n] = __builtin_amdgcn_mfma_f32_16x16x32_bf16(          \
                    Ac[4 + m], b1[n], acc[m][n], 0, 0, 0);                    \
        __builtin_amdgcn_s_setprio(0);                                        \
        if ((tt) + 1 < NT) {                                                  \
            if ((tt) + 2 < NT) {                                              \
                asm volatile("s_waitcnt vmcnt(12)" ::: "memory");             \
            } else {                                                          \
                asm volatile("s_waitcnt vmcnt(0)" ::: "memory");              \
            }                                                                 \
            __builtin_amdgcn_sched_barrier(0);                                \
            __builtin_amdgcn_s_barrier();                                     \
        }                                                                     \
    }

    // prologue: queue = [B0(4), A0(8), B1(4), A1(8)]; vmcnt(12) completes
    // {B0, A0}, leaves {B1, A1} in flight.
    STAGE_B(0);
    LOADA(A0, 0);
    if (NT > 1) {
        STAGE_B(1);
        LOADA(A1, 1);
        asm volatile("s_waitcnt vmcnt(12)" ::: "memory");
    } else {
        asm volatile("s_waitcnt vmcnt(0)" ::: "memory");
    }
    __builtin_amdgcn_sched_barrier(0);
    __builtin_amdgcn_s_barrier();

    int t = 0;
    for (; t + 3 <= NT; t += 3) {
        TILE(t, A0, A2);
        TILE(t + 1, A1, A0);
        TILE(t + 2, A2, A1);
    }
    if (t < NT) {
        TILE(t, A0, A2);
        if (t + 1 < NT) TILE(t + 1, A1, A0);
    }
#undef LOADA
#undef STAGE_B
#undef TILE

    // ---------------- epilogue: bias + relu + val interleave ----------------
    const int gmb = m0 + wr * 64;
    const int gnb = n0 + wc * 64;
    float bcol[4];
#pragma unroll
    for (int n = 0; n < 4; ++n) bcol[n] = bias[gnb + n * 16 + lrow];
#pragma unroll
    for (int m = 0; m < 4; ++m) {
#pragma unroll
        for (int r = 0; r < 4; ++r) {
            const int row = gmb + m * 16 + lkg * 4 + r;
            const float vr = val[row];
            float2* orow = (float2*)(out + (size_t)row * N * 2);
#pragma unroll
            for (int n = 0; n < 4; ++n) {
                const int col = gnb + n * 16 + lrow;
                float a = fmaxf(acc[m][n][r] + bcol[n], 0.f);
                orow[col] = make_float2(a, vr);
            }
        }
    }
}

// ---- fallback kernels (small ws): r0 path, known-correct ----
__global__ __launch_bounds__(256) void convert_x_stats(
    const float4* __restrict__ x4, uint32_t* __restrict__ abf,
    float* __restrict__ val, int din) {
    const int row = blockIdx.x;
    const int t = threadIdx.x;
    const int f4pr = din >> 1;
    const float4* xr = x4 + (size_t)row * f4pr;
    float s = 0.f;
    for (int i = t; i < f4pr; i += 256) {
        float4 v = xr[i];
        s += (v.x + v.y) + (v.z + v.w);
    }
#pragma unroll
    for (int off = 32; off; off >>= 1) s += __shfl_down(s, off, 64);
    __shared__ float red[4];
    if ((t & 63) == 0) red[t >> 6] = s;
    __syncthreads();
    if (t == 0) val[row] = (red[0] + red[1] + red[2] + red[3]) / (float)(2 * din);
}

__global__ __launch_bounds__(256) void gemm_fallback(
    const float* __restrict__ xf, const float* __restrict__ Wf,
    const float* __restrict__ bias, const float* __restrict__ val,
    float* __restrict__ out, int M, int N, int K) {
    __shared__ uint16_t lA[128 * 32];
    __shared__ uint16_t lB[128 * 32];
    const int tid = threadIdx.x;
    const int wv = tid >> 6;
    const int lane = tid & 63;
    const int lrow = lane & 15;
    const int lkg = lane >> 4;
    const int m0 = blockIdx.y * 128;
    const int n0 = blockIdx.x * 128;
    const int wr = wv >> 1, wc = wv & 1;
    f32x4_t acc[4][4];
#pragma unroll
    for (int i = 0; i < 4; ++i)
#pragma unroll
        for (int j = 0; j < 4; ++j) acc[i][j] = (f32x4_t){0.f, 0.f, 0.f, 0.f};
    for (int k0 = 0; k0 < K; k0 += 32) {
        float4 va[8];
        float4 vb[4];
#pragma unroll
        for (int i = 0; i < 8; ++i) {
            const int p = i * 256 + tid;
            const int row = p >> 4, pc = p & 15;
            va[i] = *(const float4*)(xf + ((size_t)(m0 + row) * K + k0 + pc * 2) * 2);
        }
#pragma unroll
        for (int i = 0; i < 4; ++i) {
            const int q = i * 256 + tid;
            const int row = q >> 3, qc = q & 7;
            vb[i] = *(const float4*)(Wf + (size_t)(n0 + row) * K + k0 + qc * 4);
        }
        __syncthreads();
#pragma unroll
        for (int i = 0; i < 8; ++i) {
            const int p = i * 256 + tid;
            const int row = p >> 4, pc = p & 15;
            *(uint32_t*)&lA[row * 32 + pc * 2] =
                f32_to_bf16_rne(va[i].x) | (f32_to_bf16_rne(va[i].z) << 16);
        }
#pragma unroll
        for (int i = 0; i < 4; ++i) {
            const int q = i * 256 + tid;
            const int row = q >> 3, qc = q & 7;
            uint2 pk;
            pk.x = f32_to_bf16_rne(vb[i].x) | (f32_to_bf16_rne(vb[i].y) << 16);
            pk.y = f32_to_bf16_rne(vb[i].z) | (f32_to_bf16_rne(vb[i].w) << 16);
            *(uint2*)&lB[row * 32 + qc * 4] = pk;
        }
        __syncthreads();
        bf16x8_t af[4], bfr[4];
#pragma unroll
        for (int i = 0; i < 4; ++i)
            af[i] = *(const bf16x8_t*)&lA[(wr * 64 + i * 16 + lrow) * 32 + lkg * 8];
#pragma unroll
        for (int j = 0; j < 4; ++j)
            bfr[j] = *(const bf16x8_t*)&lB[(wc * 64 + j * 16 + lrow) * 32 + lkg * 8];
#pragma unroll
        for (int i = 0; i < 4; ++i)
#pragma unroll
            for (int j = 0; j < 4; ++j)
                acc[i][j] = __builtin_amdgcn_mfma_f32_16x16x32_bf16(af[i], bfr[j],
                                                                    acc[i][j], 0, 0, 0);
        __syncthreads();
    }
    const int gm = m0 + wr * 64;
    const int gn = n0 + wc * 64;
    float bcol[4];
#pragma unroll
    for (int j = 0; j < 4; ++j) bcol[j] = bias[gn + j * 16 + lrow];
#pragma unroll
    for (int i = 0; i < 4; ++i) {
#pragma unroll
        for (int r = 0; r < 4; ++r) {
            const int row = gm + i * 16 + lkg * 4 + r;
            const float vr = val[row];
            float2* orow = (float2*)(out + (size_t)row * N * 2);
#pragma unroll
            for (int j = 0; j < 4; ++j) {
                const int col = gn + j * 16 + lrow;
                float a = fmaxf(acc[i][j][r] + bcol[j], 0.f);
                orow[col] = make_float2(a, vr);
            }
        }
    }
}

extern "C" void kernel_launch(void* const* d_in, const int* in_sizes, int n_in,
                              void* d_out, int out_size, void* d_ws, size_t ws_size,
                              hipStream_t stream) {
    const float* x = (const float*)d_in[0];     // [B, DIN, 2]
    const float* W = (const float*)d_in[1];     // [DOUT, DIN]
    const float* b = (const float*)d_in[2];     // [DOUT]
    float* out = (float*)d_out;                 // [B, DOUT, 2]

    const int DOUT = in_sizes[2];
    const int DIN = in_sizes[1] / DOUT;
    const int B = in_sizes[0] / (2 * DIN);

    float* val = (float*)d_ws;
    const size_t aoff = 8192;
    const size_t abytes = (size_t)B * DIN * 2;
    const size_t wbytes = (size_t)DOUT * DIN * 2;
    const bool big = ws_size >= aoff + abytes + wbytes &&
                     (B % 128) == 0 && (DOUT % 128) == 0 && (DIN % 128) == 0;

    if (big) {
        uint4* abf = (uint4*)((char*)d_ws + aoff);
        uint32_t* wbf = (uint32_t*)((char*)d_ws + aoff + abytes);

        (void)hipMemsetAsync(val, 0, (size_t)B * sizeof(float), stream);

        const int osteps = DIN / 128;
        int split = 1;
        for (int c : {16, 8, 4, 2}) { if (osteps % c == 0) { split = c; break; } }
        const int spb = osteps / split;
        dim3 gx(B / 16, split);
        convert_x_frag<<<gx, 256, 0, stream>>>(x, abf, val, DIN, spb);

        const int n4 = DOUT * DIN / 4;
        convert_w<<<(n4 + 255) / 256, 256, 0, stream>>>((const float4*)W, (uint2*)wbf, n4);

        (void)hipFuncSetAttribute((const void*)gemm_hyb,
                                  hipFuncAttributeMaxDynamicSharedMemorySize, LDS_BYTES);
        dim3 grid(DOUT / 128, B / 128);
        gemm_hyb<<<grid, 256, LDS_BYTES, stream>>>(abf, (const uint16_t*)wbf,
                                                   b, val, out, B, DOUT, DIN);
    } else {
        convert_x_stats<<<B, 256, 0, stream>>>((const float4*)x, nullptr, val, DIN);
        dim3 grid(DOUT / 128, B / 128);
        gemm_fallback<<<grid, 256, 0, stream>>>(x, W, b, val, out, B, DOUT, DIN);
    }
}